// Round 1
// baseline (107.115 us; speedup 1.0000x reference)
//
#include <hip/hip_runtime.h>

// InverseHaarUpsample: x [B=16, 4*C=256, H=128, W=128] f32 -> out [16, 64, 256, 256] f32
// out[b,c,2h+p,2w+q] = sum_s x[b, s*64+c, h, w] * haar[s][p][q]
// haar/2: LL=[[.5,.5],[.5,.5]], LH=[[-.5,-.5],[.5,.5]], HL=[[-.5,.5],[-.5,.5]], HH=[[.5,-.5],[-.5,.5]]

__global__ __launch_bounds__(256) void ihaar_up_kernel(const float* __restrict__ x,
                                                       float* __restrict__ out) {
    // One thread handles 2 horizontally-adjacent input pixels.
    // Layout of flat thread id t (total 16*64*128*64 = 2^23 threads):
    //   bits [0:6)  = w2  (float2 index within input row, 0..63)
    //   bits [6:13) = h   (0..127)
    //   bits[13:19) = c   (0..63)
    //   bits[19:23) = b   (0..15)
    const unsigned t  = blockIdx.x * 256u + threadIdx.x;
    const unsigned w2 = t & 63u;
    const unsigned h  = (t >> 6) & 127u;
    const unsigned c  = (t >> 13) & 63u;
    const unsigned b  = t >> 19;

    const size_t plane   = 128u * 128u;                      // per-channel input plane
    const size_t in_base = ((size_t)(b * 256u + c)) * plane  // subband 0 channel
                         + (size_t)h * 128u + (size_t)w2 * 2u;

    const float2 ll = *(const float2*)(x + in_base);
    const float2 lh = *(const float2*)(x + in_base +  64u * plane);
    const float2 hl = *(const float2*)(x + in_base + 128u * plane);
    const float2 hh = *(const float2*)(x + in_base + 192u * plane);

    float4 r0, r1;
    {
        const float a = ll.x, e = lh.x, f = hl.x, g = hh.x;
        const float apE = a + e, amE = a - e;   // a±e
        const float fpG = f + g, fmG = f - g;   // f±g
        r0.x = 0.5f * (amE - fmG);   // a - e - f + g
        r0.y = 0.5f * (amE + fmG);   // a - e + f - g
        r1.x = 0.5f * (apE - fpG);   // a + e - f - g
        r1.y = 0.5f * (apE + fpG);   // a + e + f + g
    }
    {
        const float a = ll.y, e = lh.y, f = hl.y, g = hh.y;
        const float apE = a + e, amE = a - e;
        const float fpG = f + g, fmG = f - g;
        r0.z = 0.5f * (amE - fmG);
        r0.w = 0.5f * (amE + fmG);
        r1.z = 0.5f * (apE - fpG);
        r1.w = 0.5f * (apE + fpG);
    }

    const size_t orow     = 256u;
    const size_t out_base = ((size_t)(b * 64u + c)) * (256u * 256u)
                          + (size_t)(2u * h) * orow + (size_t)w2 * 4u;
    *(float4*)(out + out_base)        = r0;   // output row 2h
    *(float4*)(out + out_base + orow) = r1;   // output row 2h+1
}

extern "C" void kernel_launch(void* const* d_in, const int* in_sizes, int n_in,
                              void* d_out, int out_size, void* d_ws, size_t ws_size,
                              hipStream_t stream) {
    const float* x = (const float*)d_in[0];
    float* out     = (float*)d_out;
    // total threads = 16 * 64 * 128 * 64 = 8,388,608 -> 32768 blocks of 256
    const unsigned nthreads = 16u * 64u * 128u * 64u;
    ihaar_up_kernel<<<nthreads / 256u, 256u, 0, stream>>>(x, out);
}

// Round 3
// 90.281 us; speedup vs baseline: 1.1865x; 1.1865x over previous
//
#include <hip/hip_runtime.h>

// InverseHaarUpsample: x [B=16, 4*C=256, H=128, W=128] f32 -> out [16, 64, 256, 256] f32
// out[b,c,2h+p,2w+q] = sum_s x[b, s*64+c, h, w] * haar[s][p][q]
// Pure streaming op (zero reuse) -> nontemporal loads/stores, max bytes/thread.

typedef float v2f __attribute__((ext_vector_type(2)));
typedef float v4f __attribute__((ext_vector_type(4)));

__device__ __forceinline__ v2f ntl2(const float* p) {
    return __builtin_nontemporal_load((const v2f*)p);
}

// One input pixel-pair (ll,lh,hl,hh as v2f) -> two output v4f (rows 2h, 2h+1)
__device__ __forceinline__ void haar2(const v2f ll, const v2f lh,
                                      const v2f hl, const v2f hh,
                                      v4f& r0, v4f& r1) {
    {
        const float a = ll.x, e = lh.x, f = hl.x, g = hh.x;
        const float apE = a + e, amE = a - e;
        const float fpG = f + g, fmG = f - g;
        r0.x = 0.5f * (amE - fmG);   // a - e - f + g
        r0.y = 0.5f * (amE + fmG);   // a - e + f - g
        r1.x = 0.5f * (apE - fpG);   // a + e - f - g
        r1.y = 0.5f * (apE + fpG);   // a + e + f + g
    }
    {
        const float a = ll.y, e = lh.y, f = hl.y, g = hh.y;
        const float apE = a + e, amE = a - e;
        const float fpG = f + g, fmG = f - g;
        r0.z = 0.5f * (amE - fmG);
        r0.w = 0.5f * (amE + fmG);
        r1.z = 0.5f * (apE - fpG);
        r1.w = 0.5f * (apE + fpG);
    }
}

__global__ __launch_bounds__(256) void ihaar_up_kernel(const float* __restrict__ x,
                                                       float* __restrict__ out) {
    // Each thread: 2 horizontally-adjacent pixels x 2 vertically-adjacent rows.
    // Flat thread id t (total 2^22 threads):
    //   bits [0:6)   = w2  (float2 index within input row, 0..63)
    //   bits [6:12)  = h2  (input row-pair index, 0..63; rows 2*h2, 2*h2+1)
    //   bits [12:18) = c   (0..63)
    //   bits [18:22) = b   (0..15)
    const unsigned t  = blockIdx.x * 256u + threadIdx.x;
    const unsigned w2 = t & 63u;
    const unsigned h2 = (t >> 6) & 63u;
    const unsigned c  = (t >> 12) & 63u;
    const unsigned b  = t >> 18;

    const size_t plane = 128u * 128u;  // per-channel input plane (floats)
    const float* p = x + ((size_t)(b * 256u + c)) * plane
                       + (size_t)(2u * h2) * 128u + (size_t)w2 * 2u;

    // 8 independent 8B loads -> 64 B in flight per thread
    const v2f ll0 = ntl2(p);
    const v2f ll1 = ntl2(p + 128);
    const v2f lh0 = ntl2(p +  64u * plane);
    const v2f lh1 = ntl2(p +  64u * plane + 128);
    const v2f hl0 = ntl2(p + 128u * plane);
    const v2f hl1 = ntl2(p + 128u * plane + 128);
    const v2f hh0 = ntl2(p + 192u * plane);
    const v2f hh1 = ntl2(p + 192u * plane + 128);

    v4f r0, r1, r2, r3;
    haar2(ll0, lh0, hl0, hh0, r0, r1);   // -> output rows 4*h2, 4*h2+1
    haar2(ll1, lh1, hl1, hh1, r2, r3);   // -> output rows 4*h2+2, 4*h2+3

    float* q = out + ((size_t)(b * 64u + c)) * (256u * 256u)
                   + (size_t)(4u * h2) * 256u + (size_t)w2 * 4u;
    __builtin_nontemporal_store(r0, (v4f*)(q));
    __builtin_nontemporal_store(r1, (v4f*)(q + 256));
    __builtin_nontemporal_store(r2, (v4f*)(q + 512));
    __builtin_nontemporal_store(r3, (v4f*)(q + 768));
}

extern "C" void kernel_launch(void* const* d_in, const int* in_sizes, int n_in,
                              void* d_out, int out_size, void* d_ws, size_t ws_size,
                              hipStream_t stream) {
    const float* x = (const float*)d_in[0];
    float* out     = (float*)d_out;
    // total threads = 2^22 -> 16384 blocks of 256
    ihaar_up_kernel<<<16384, 256, 0, stream>>>(x, out);
}